// Round 21
// baseline (299.567 us; speedup 1.0000x reference)
//
#include <hip/hip_runtime.h>
#include <hip/hip_bf16.h>
#include <stdint.h>

#define AS1 __attribute__((address_space(1)))
#define AS3 __attribute__((address_space(3)))

typedef float f32x4 __attribute__((ext_vector_type(4)));
typedef __bf16 bf16x8 __attribute__((ext_vector_type(8)));

static __device__ __forceinline__ unsigned short f2bf(float f) {
  unsigned u = __float_as_uint(f);
  u += 0x7fff + ((u >> 16) & 1);   // RNE
  return (unsigned short)(u >> 16);
}
static __device__ __forceinline__ float bf2f_lo(unsigned u) { return __uint_as_float(u << 16); }
static __device__ __forceinline__ float bf2f_hi(unsigned u) { return __uint_as_float(u & 0xffff0000u); }

// ------------- merged conversion: query and target in one dispatch ----------

__global__ __launch_bounds__(256) void k_conv2(const float* __restrict__ a,
                                               const float* __restrict__ b,
                                               unsigned short* __restrict__ oa,
                                               unsigned short* __restrict__ ob) {
  int i = blockIdx.x * 256 + threadIdx.x;          // 0..4194303 (float4 units)
  const float* in;
  unsigned short* out;
  int idx;
  if (i < 2097152) { in = a; out = oa; idx = i; }
  else             { in = b; out = ob; idx = i - 2097152; }
  float4 v = reinterpret_cast<const float4*>(in)[idx];
  ushort4 o;
  o.x = f2bf(v.x); o.y = f2bf(v.y); o.z = f2bf(v.z); o.w = f2bf(v.w);
  reinterpret_cast<ushort4*>(out)[idx] = o;
}

// transpose + convert the four 512x512 weights: out[n*512+k] = bf16(w[k*512+n])
__global__ __launch_bounds__(256) void k_wtrans(const float* __restrict__ w0, const float* __restrict__ w1,
                                                const float* __restrict__ w2, const float* __restrict__ w3,
                                                unsigned short* __restrict__ o0, unsigned short* __restrict__ o1,
                                                unsigned short* __restrict__ o2, unsigned short* __restrict__ o3) {
  const float* w; unsigned short* o;
  switch (blockIdx.y) {
    case 0: w = w0; o = o0; break;
    case 1: w = w1; o = o1; break;
    case 2: w = w2; o = o2; break;
    default: w = w3; o = o3; break;
  }
  int idx = blockIdx.x * 256 + threadIdx.x;   // 0..262143
  int kk = idx >> 9;
  int n  = idx & 511;
  o[n * 512 + kk] = f2bf(w[idx]);
}

// ---- V transpose: v_row[16384][512] -> v_t[b][512][4096], 64x64 LDS tiles ----

__global__ __launch_bounds__(256) void k_vtrans(const unsigned short* __restrict__ vr,
                                                unsigned short* __restrict__ vt) {
  __shared__ unsigned short lds[64 * 66];    // pad 66: bank-friendly
  const int tid = threadIdx.x;
  const int d0 = blockIdx.x * 64;            // 0..448
  const int s0 = blockIdx.y * 64;            // 0..16320 (tile within one batch)
  const int r = tid >> 4;                    // 0..15
  const int c4 = (tid & 15) * 4;             // 0,4,...,60
#pragma unroll
  for (int i = 0; i < 4; ++i) {
    const int row = i * 16 + r;              // s-offset in tile
    ushort4 v = *reinterpret_cast<const ushort4*>(&vr[(size_t)(s0 + row) * 512 + d0 + c4]);
    lds[row * 66 + c4 + 0] = v.x;
    lds[row * 66 + c4 + 1] = v.y;
    lds[row * 66 + c4 + 2] = v.z;
    lds[row * 66 + c4 + 3] = v.w;
  }
  __syncthreads();
  const int b = s0 >> 12;
  const int sin = s0 & 4095;
#pragma unroll
  for (int i = 0; i < 4; ++i) {
    const int drow = i * 16 + r;             // d-offset in tile
    ushort4 o;
    o.x = lds[(c4 + 0) * 66 + drow];
    o.y = lds[(c4 + 1) * 66 + drow];
    o.z = lds[(c4 + 2) * 66 + drow];
    o.w = lds[(c4 + 3) * 66 + drow];
    *reinterpret_cast<ushort4*>(&vt[(size_t)b * 2097152u + (size_t)(d0 + drow) * 4096u
                                    + sin + c4]) = o;
  }
}

// ---------------- shared GEMM body (EXACT R11 form, unchanged) --------------

template<int EPI, int HAS_BIAS, int SPLITK>
static __device__ __forceinline__ void gemm_body(
    const unsigned short* __restrict__ A, int lda,
    const unsigned short* __restrict__ Bt, int ldb,
    const float* __restrict__ bias,
    void* __restrict__ Cout,
    int ldc, int kLen, int partStride)
{
  __shared__ __align__(16) unsigned short sA[128 * 32];
  __shared__ __align__(16) unsigned short sB[128 * 32];

  const int nx = gridDim.x, ny = gridDim.y;
  const int nwg = nx * ny * gridDim.z;
  const int bid = blockIdx.x + nx * (blockIdx.y + ny * blockIdx.z);
  const int wg = (bid & 7) * (nwg >> 3) + (bid >> 3);
  const int bx = wg % nx;
  const int tmp = wg / nx;
  const int by = tmp % ny;
  const int bz = tmp / ny;

  float* CoutF = (float*)Cout;
  if (SPLITK) {
    A  += (size_t)bz * kLen;
    Bt += (size_t)bz * kLen;
    CoutF += (size_t)bz * partStride;
  }

  const int tid = threadIdx.x;
  const int tileM = by * 128;
  const int tileN = bx * 128;
  const unsigned short* Ab = A + (size_t)tileM * lda;
  const unsigned short* Bb = Bt + (size_t)tileN * ldb;

  f32x4 acc[4][4];
#pragma unroll
  for (int m = 0; m < 4; ++m)
#pragma unroll
    for (int n = 0; n < 4; ++n)
      acc[m][n] = (f32x4){0.f, 0.f, 0.f, 0.f};

  const int lane = tid & 63;
  const int w = tid >> 6;
  const int wr = (w >> 1) * 64;
  const int wc = (w & 1) * 64;
  const int fr = lane & 15;
  const int fk = (lane >> 4) * 8;

  for (int k0 = 0; k0 < kLen; k0 += 32) {
    __syncthreads();
#pragma unroll
    for (int i = 0; i < 2; ++i) {
      int c = tid + i * 256;         // 0..511 (16B chunks)
      int r = c >> 2;
      int cb = (c & 3) * 8;
      __builtin_amdgcn_global_load_lds((const AS1 void*)(Ab + (size_t)r * lda + k0 + cb),
                                       (AS3 void*)(&sA[c * 8]), 16, 0, 0);
      __builtin_amdgcn_global_load_lds((const AS1 void*)(Bb + (size_t)r * ldb + k0 + cb),
                                       (AS3 void*)(&sB[c * 8]), 16, 0, 0);
    }
    __syncthreads();

    bf16x8 af[4], bfr[4];
#pragma unroll
    for (int m = 0; m < 4; ++m)
      af[m] = *reinterpret_cast<const bf16x8*>(&sA[(wr + m * 16 + fr) * 32 + fk]);
#pragma unroll
    for (int n = 0; n < 4; ++n)
      bfr[n] = *reinterpret_cast<const bf16x8*>(&sB[(wc + n * 16 + fr) * 32 + fk]);
#pragma unroll
    for (int m = 0; m < 4; ++m)
#pragma unroll
      for (int n = 0; n < 4; ++n)
        acc[m][n] = __builtin_amdgcn_mfma_f32_16x16x32_bf16(af[m], bfr[n], acc[m][n], 0, 0, 0);
  }

  const int col4 = lane & 15;
  const int rw4 = (lane >> 4) * 4;
#pragma unroll
  for (int n = 0; n < 4; ++n) {
    const int gc = tileN + wc + n * 16 + col4;
    const float bval = HAS_BIAS ? bias[gc] : 0.0f;
#pragma unroll
    for (int m = 0; m < 4; ++m) {
      const int gr0 = tileM + wr + m * 16 + rw4;
#pragma unroll
      for (int j = 0; j < 4; ++j) {
        const int gr = gr0 + j;
        float v = acc[m][n][j] + bval;
        if (EPI == 1) {
          CoutF[(size_t)gr * ldc + gc] = v;
        } else {
          ((unsigned short*)Cout)[(size_t)gr * ldc + gc] = f2bf(v);
        }
      }
    }
  }
}

// ------------- named kernel wrappers (R11 codegen preserved) ----------------

__global__ __launch_bounds__(256) void k_pv(
    const unsigned short* __restrict__ E, const unsigned short* __restrict__ Vt,
    float* __restrict__ part) {
  gemm_body<1, 0, 1>(E, 4096, Vt, 4096, nullptr, part, 512, 1024, 4096 * 512);
}

__global__ __launch_bounds__(256) void k_oproj(
    const unsigned short* __restrict__ A, const unsigned short* __restrict__ Bt,
    const float* __restrict__ bias, float* __restrict__ C) {
  gemm_body<1, 1, 0>(A, 512, Bt, 512, bias, C, 512, 512, 0);
}

// -------- standalone batched S-GEMM: E[bz] = exp(Q[bz] K[bz]^T) -------------
// NEW this round: BK=64 (16 -> 8 K-steps, halved barrier drains) with
// rule-21-compliant XOR chunk swizzle: LDS dest stays LINEAR (required by
// global_load_lds); the per-lane GLOBAL source fetches chunk j^(r&7) into
// slot j of row r, and ds_read applies the same XOR. Bank trace: read dword
// = r*32 + j*4 + d with j spanning 8 values across 16 lanes -> 2 lanes/bank
// (free, m136) vs the old BK=32 layout's 8-way conflict (8.4M measured).
// Epilogue unchanged (plain scalar stores — R17 proved restage loses here).

__global__ __launch_bounds__(256) void k_sexp4(
    const unsigned short* __restrict__ Q, const unsigned short* __restrict__ K,
    unsigned short* __restrict__ E)
{
  __shared__ __align__(16) unsigned short sA[128 * 64];   // 16 KB
  __shared__ __align__(16) unsigned short sB[128 * 64];   // 16 KB

  const int nwg = 1024 * gridDim.z;
  const int bid = blockIdx.x + 32 * (blockIdx.y + 32 * blockIdx.z);
  const int wg = (bid & 7) * (nwg >> 3) + (bid >> 3);
  const int bx = wg & 31;
  const int by = (wg >> 5) & 31;
  const int bz = wg >> 10;

  const int tid = threadIdx.x;
  const int tileM = by * 128;
  const int tileN = bx * 128;
  const unsigned short* Ab = Q + (size_t)bz * 2097152u + (size_t)tileM * 512;
  const unsigned short* Bb = K + (size_t)bz * 2097152u + (size_t)tileN * 512;
  unsigned short* Eb = E + (size_t)bz * 16777216u;

  f32x4 acc[4][4];
#pragma unroll
  for (int m = 0; m < 4; ++m)
#pragma unroll
    for (int n = 0; n < 4; ++n)
      acc[m][n] = (f32x4){0.f, 0.f, 0.f, 0.f};

  const int lane = tid & 63;
  const int w = tid >> 6;
  const int wr = (w >> 1) * 64;
  const int wc = (w & 1) * 64;
  const int fr = lane & 15;
  const int fk8 = lane >> 4;        // 0..3: which 8-elem chunk of a 32-k slice

  for (int k0 = 0; k0 < 512; k0 += 64) {
    __syncthreads();
#pragma unroll
    for (int i = 0; i < 4; ++i) {
      int c = tid + i * 256;        // LDS chunk slot 0..1023
      int r = c >> 3;               // row 0..127
      int j = c & 7;                // slot within row
      int g = j ^ (r & 7);          // global chunk (XOR involution)
      __builtin_amdgcn_global_load_lds((const AS1 void*)(Ab + (size_t)r * 512 + k0 + g * 8),
                                       (AS3 void*)(&sA[c * 8]), 16, 0, 0);
      __builtin_amdgcn_global_load_lds((const AS1 void*)(Bb + (size_t)r * 512 + k0 + g * 8),
                                       (AS3 void*)(&sB[c * 8]), 16, 0, 0);
    }
    __syncthreads();

#pragma unroll
    for (int kk = 0; kk < 2; ++kk) {
      bf16x8 af[4], bfr[4];
#pragma unroll
      for (int m = 0; m < 4; ++m) {
        const int r = wr + m * 16 + fr;
        af[m] = *reinterpret_cast<const bf16x8*>(
            &sA[(r * 8 + ((kk * 4 + fk8) ^ (r & 7))) * 8]);
      }
#pragma unroll
      for (int n = 0; n < 4; ++n) {
        const int r = wc + n * 16 + fr;
        bfr[n] = *reinterpret_cast<const bf16x8*>(
            &sB[(r * 8 + ((kk * 4 + fk8) ^ (r & 7))) * 8]);
      }
#pragma unroll
      for (int m = 0; m < 4; ++m)
#pragma unroll
        for (int n = 0; n < 4; ++n)
          acc[m][n] = __builtin_amdgcn_mfma_f32_16x16x32_bf16(af[m], bfr[n], acc[m][n], 0, 0, 0);
    }
  }

  const int col4 = lane & 15;
  const int rw4 = (lane >> 4) * 4;
#pragma unroll
  for (int n = 0; n < 4; ++n) {
    const int gc = tileN + wc + n * 16 + col4;
#pragma unroll
    for (int m = 0; m < 4; ++m) {
      const int gr0 = tileM + wr + m * 16 + rw4;
#pragma unroll
      for (int j = 0; j < 4; ++j)
        Eb[(size_t)(gr0 + j) * 4096 + gc] = f2bf(__expf(acc[m][n][j]));
    }
  }
}

// -------- standalone merged PV (NB=4 path): part[bz] = E-chunk @ V-chunk -----
// R19-validated: one dispatch, 4 batches x 2 K-chunks, fused lsum on bx==0.

__global__ __launch_bounds__(256) void k_pv4(
    const unsigned short* __restrict__ E, const unsigned short* __restrict__ Vt,
    float* __restrict__ part, float* __restrict__ lsumPart)
{
  __shared__ __align__(16) unsigned short sA[128 * 32];
  __shared__ __align__(16) unsigned short sB[128 * 32];

  const int nwg = 1024;
  const int bid = blockIdx.x + 4 * (blockIdx.y + 32 * blockIdx.z);
  const int wg = (bid & 7) * (nwg >> 3) + (bid >> 3);
  const int bx = wg & 3;
  const int tmp = wg >> 2;
  const int by = tmp & 31;
  const int bz = tmp >> 5;          // 0..7
  const int batch = bz >> 1;
  const int kc = bz & 1;

  const int tid = threadIdx.x;
  const int tileM = by * 128;
  const int tileN = bx * 128;
  const unsigned short* Ab = E + (size_t)batch * 16777216u + (size_t)tileM * 4096 + kc * 2048;
  const unsigned short* Bb = Vt + (size_t)batch * 2097152u + (size_t)tileN * 4096 + kc * 2048;
  float* CoutF = part + (size_t)bz * 2097152u;

  f32x4 acc[4][4];
#pragma unroll
  for (int m = 0; m < 4; ++m)
#pragma unroll
    for (int n = 0; n < 4; ++n)
      acc[m][n] = (f32x4){0.f, 0.f, 0.f, 0.f};

  const int lane = tid & 63;
  const int w = tid >> 6;
  const int wr = (w >> 1) * 64;
  const int wc = (w & 1) * 64;
  const int fr = lane & 15;
  const int fk = (lane >> 4) * 8;

  float rs0 = 0.f, rs1 = 0.f;

  for (int k0 = 0; k0 < 2048; k0 += 32) {
    __syncthreads();
#pragma unroll
    for (int i = 0; i < 2; ++i) {
      int c = tid + i * 256;
      int r = c >> 2;
      int cb = (c & 3) * 8;
      __builtin_amdgcn_global_load_lds((const AS1 void*)(Ab + (size_t)r * 4096 + k0 + cb),
                                       (AS3 void*)(&sA[c * 8]), 16, 0, 0);
      __builtin_amdgcn_global_load_lds((const AS1 void*)(Bb + (size_t)r * 4096 + k0 + cb),
                                       (AS3 void*)(&sB[c * 8]), 16, 0, 0);
    }
    __syncthreads();

    if (bx == 0) {
      uint4 u0 = *reinterpret_cast<const uint4*>(&sA[tid * 8]);
      uint4 u1 = *reinterpret_cast<const uint4*>(&sA[(tid + 256) * 8]);
      rs0 += bf2f_lo(u0.x) + bf2f_hi(u0.x) + bf2f_lo(u0.y) + bf2f_hi(u0.y)
           + bf2f_lo(u0.z) + bf2f_hi(u0.z) + bf2f_lo(u0.w) + bf2f_hi(u0.w);
      rs1 += bf2f_lo(u1.x) + bf2f_hi(u1.x) + bf2f_lo(u1.y) + bf2f_hi(u1.y)
           + bf2f_lo(u1.z) + bf2f_hi(u1.z) + bf2f_lo(u1.w) + bf2f_hi(u1.w);
    }

    bf16x8 af[4], bfr[4];
#pragma unroll
    for (int m = 0; m < 4; ++m)
      af[m] = *reinterpret_cast<const bf16x8*>(&sA[(wr + m * 16 + fr) * 32 + fk]);
#pragma unroll
    for (int n = 0; n < 4; ++n)
      bfr[n] = *reinterpret_cast<const bf16x8*>(&sB[(wc + n * 16 + fr) * 32 + fk]);
#pragma unroll
    for (int m = 0; m < 4; ++m)
#pragma unroll
      for (int n = 0; n < 4; ++n)
        acc[m][n] = __builtin_amdgcn_mfma_f32_16x16x32_bf16(af[m], bfr[n], acc[m][n], 0, 0, 0);
  }

  if (bx == 0) {
    rs0 += __shfl_xor(rs0, 1); rs0 += __shfl_xor(rs0, 2);
    rs1 += __shfl_xor(rs1, 1); rs1 += __shfl_xor(rs1, 2);
    if ((tid & 3) == 0) {
      lsumPart[(size_t)bz * 4096 + tileM + (tid >> 2)] = rs0;
      lsumPart[(size_t)bz * 4096 + tileM + (tid >> 2) + 64] = rs1;
    }
  }

  const int col4 = lane & 15;
  const int rw4 = (lane >> 4) * 4;
#pragma unroll
  for (int n = 0; n < 4; ++n) {
    const int gc = tileN + wc + n * 16 + col4;
#pragma unroll
    for (int m = 0; m < 4; ++m) {
      const int gr0 = tileM + wr + m * 16 + rw4;
#pragma unroll
      for (int j = 0; j < 4; ++j)
        CoutF[(size_t)(gr0 + j) * 512 + gc] = acc[m][n][j];
    }
  }
}

// -------- standalone merged Q/K/V projection (R20-validated) ----------------

__global__ __launch_bounds__(256) void k_proj_all(
    const unsigned short* __restrict__ Qin, const unsigned short* __restrict__ Tin,
    const unsigned short* __restrict__ wq_t, const unsigned short* __restrict__ wkv_t,
    const float* __restrict__ bq, const float* __restrict__ bk, const float* __restrict__ bv,
    unsigned short* __restrict__ Qout, unsigned short* __restrict__ Kout,
    unsigned short* __restrict__ Vrow)
{
  __shared__ __align__(16) unsigned short smem[8704];  // sA=[0,4096), sB=[4096,8192); sC reuse

  const int nx = 12, ny = 128;
  const int nwg = nx * ny;                   // 1536, %8==0
  const int bid = blockIdx.x + nx * blockIdx.y;
  const int wg = (bid & 7) * (nwg >> 3) + (bid >> 3);
  const int bx = wg % nx;
  const int by = wg / nx;

  const int tid = threadIdx.x;
  const int tileM = by * 128;
  const unsigned short* A = (bx < 4) ? Qin : Tin;
  const unsigned short* Bt;
  int tileN;
  if (bx < 4) { Bt = wq_t;  tileN = bx * 128; }
  else        { Bt = wkv_t; tileN = (bx - 4) * 128; }
  const unsigned short* Ab = A + (size_t)tileM * 512;
  const unsigned short* Bb = Bt + (size_t)tileN * 512;

  f32x4 acc[4][4];
#pragma unroll
  for (int m = 0; m < 4; ++m)
#pragma unroll
    for (int n = 0; n < 4; ++n)
      acc[m][n] = (f32x4){0.f, 0.f, 0.f, 0.f};

  const int lane = tid & 63;
  const int w = tid >> 6;
  const int wr = (w >> 1) * 64;
  const int wc = (w & 1) * 64;
  const int fr = lane & 15;
  const int fk = (lane >> 4) * 8;

  for (int k0 = 0; k0 < 512; k0 += 32) {
    __syncthreads();
#pragma unroll
    for (int i = 0; i < 2; ++i) {
      int c = tid + i * 256;
      int r = c >> 2;
      int cb = (c & 3) * 8;
      __builtin_amdgcn_global_load_lds((const AS1 void*)(Ab + (size_t)r * 512 + k0 + cb),
                                       (AS3 void*)(&smem[c * 8]), 16, 0, 0);
      __builtin_amdgcn_global_load_lds((const AS1 void*)(Bb + (size_t)r * 512 + k0 + cb),
                                       (AS3 void*)(&smem[4096 + c * 8]), 16, 0, 0);
    }
    __syncthreads();

    bf16x8 af[4], bfr[4];
#pragma unroll
    for (int m = 0; m < 4; ++m)
      af[m] = *reinterpret_cast<const bf16x8*>(&smem[(wr + m * 16 + fr) * 32 + fk]);
#pragma unroll
    for (int n = 0; n < 4; ++n)
      bfr[n] = *reinterpret_cast<const bf16x8*>(&smem[4096 + (wc + n * 16 + fr) * 32 + fk]);
#pragma unroll
    for (int m = 0; m < 4; ++m)
#pragma unroll
      for (int n = 0; n < 4; ++n)
        acc[m][n] = __builtin_amdgcn_mfma_f32_16x16x32_bf16(af[m], bfr[n], acc[m][n], 0, 0, 0);
  }

  const int col4 = lane & 15;
  const int rw4 = (lane >> 4) * 4;
  unsigned short* dst;
  const float* bias;
  int colbase;
  if (bx < 4)      { dst = Qout; bias = bq; colbase = tileN; }
  else if (bx < 8) { dst = Kout; bias = bk; colbase = tileN; }
  else             { dst = Vrow; bias = bv; colbase = tileN - 512; }
  const int lrow = tid >> 2;        // 0..63
  const int chunk = tid & 3;        // 4 x 32 cols
  __syncthreads();                  // MFMA LDS reads retired before sC writes
#pragma unroll
  for (int pass = 0; pass < 2; ++pass) {
    if ((w >> 1) == pass) {
#pragma unroll
      for (int m = 0; m < 4; ++m)
#pragma unroll
        for (int n = 0; n < 4; ++n) {
          const int lc = wc + n * 16 + col4;           // 0..127 within tile
          const float bval = bias[colbase + lc];
#pragma unroll
          for (int j = 0; j < 4; ++j)
            smem[(m * 16 + rw4 + j) * 136 + lc] = f2bf(acc[m][n][j] + bval);
        }
    }
    __syncthreads();
    const int grow = tileM + pass * 64 + lrow;
    unsigned short* drow = dst + (size_t)grow * 512 + colbase + chunk * 32;
#pragma unroll
    for (int i = 0; i < 4; ++i) {
      uint4 u = *reinterpret_cast<const uint4*>(&smem[lrow * 136 + chunk * 32 + i * 8]);
      *reinterpret_cast<uint4*>(drow + i * 8) = u;
    }
    __syncthreads();
  }
}

// ---------------- row sum of E (NB=2 fallback path only) --------------------

__global__ __launch_bounds__(256) void k_rowsum(const unsigned short* __restrict__ E,
                                                float* __restrict__ invl) {
  const int row = blockIdx.x;
  const uint4* p = reinterpret_cast<const uint4*>(E + (size_t)row * 4096);
  const int tid = threadIdx.x;
  float s = 0.f;
#pragma unroll
  for (int i = 0; i < 2; ++i) {
    uint4 u = p[tid + i * 256];
    s += bf2f_lo(u.x) + bf2f_hi(u.x) + bf2f_lo(u.y) + bf2f_hi(u.y)
       + bf2f_lo(u.z) + bf2f_hi(u.z) + bf2f_lo(u.w) + bf2f_hi(u.w);
  }
#pragma unroll
  for (int off = 32; off >= 1; off >>= 1) s += __shfl_xor(s, off);
  __shared__ float reds[4];
  const int wv = tid >> 6, ln = tid & 63;
  if (ln == 0) reds[wv] = s;
  __syncthreads();
  if (tid == 0) {
    float t = reds[0] + reds[1] + reds[2] + reds[3];
    invl[row] = 1.0f / t;
  }
}

// ------- merged split-K reduce + normalization (NB=4 path) ------------------

__global__ __launch_bounds__(256) void k_reduce4(const float* __restrict__ part,
                                                 const float* __restrict__ lsumPart,
                                                 unsigned short* __restrict__ ctx) {
  const int i = blockIdx.x * 256 + threadIdx.x;   // float4 idx, 2097152 total
  const int b = i >> 19;
  const int j = i & 524287;
  const int row = j >> 7;
  const float4* p = reinterpret_cast<const float4*>(part);
  float4 a = p[(size_t)(2 * b) * 524288 + j];
  float4 c = p[(size_t)(2 * b + 1) * 524288 + j];
  const float iv = 1.0f / (lsumPart[(size_t)(2 * b) * 4096 + row]
                         + lsumPart[(size_t)(2 * b + 1) * 4096 + row]);
  ushort4 o;
  o.x = f2bf((a.x + c.x) * iv); o.y = f2bf((a.y + c.y) * iv);
  o.z = f2bf((a.z + c.z) * iv); o.w = f2bf((a.w + c.w) * iv);
  reinterpret_cast<ushort4*>(ctx)[i] = o;
}

// ------- per-batch reduce (NB=2 fallback path only) -------------------------

__global__ __launch_bounds__(256) void k_reduce_ks(const float* __restrict__ part,
                                                   const float* __restrict__ invl,
                                                   unsigned short* __restrict__ out) {
  const int i = blockIdx.x * 256 + threadIdx.x;       // float4 index, 524288 total
  const float4* p = reinterpret_cast<const float4*>(part);
  float4 a = p[i];
  float4 b = p[i + 524288];
  float4 c = p[i + 2 * 524288];
  float4 d = p[i + 3 * 524288];
  const float iv = invl[i >> 7];
  float4 s;
  s.x = ((a.x + b.x) + (c.x + d.x)) * iv;
  s.y = ((a.y + b.y) + (c.y + d.y)) * iv;
  s.z = ((a.z + b.z) + (c.z + d.z)) * iv;
  s.w = ((a.w + b.w) + (c.w + d.w)) * iv;
  ushort4 o;
  o.x = f2bf(s.x); o.y = f2bf(s.y); o.z = f2bf(s.z); o.w = f2bf(s.w);
  reinterpret_cast<ushort4*>(out)[i] = o;
}

// ---------------- launch ----------------

extern "C" void kernel_launch(void* const* d_in, const int* in_sizes, int n_in,
                              void* d_out, int out_size, void* d_ws, size_t ws_size,
                              hipStream_t stream) {
  const float* query  = (const float*)d_in[0];
  const float* target = (const float*)d_in[1];
  const float* wq = (const float*)d_in[2];
  const float* bq = (const float*)d_in[3];
  const float* wk = (const float*)d_in[4];
  const float* bk = (const float*)d_in[5];
  const float* wv = (const float*)d_in[6];
  const float* bv = (const float*)d_in[7];
  const float* wo = (const float*)d_in[8];
  const float* bo = (const float*)d_in[9];
  float* out = (float*)d_out;

  const size_t SZ_BF = (size_t)16384 * 512 * 2;       // 16 MB
  const size_t SZ_SB = (size_t)4096 * 4096 * 2;       // 32 MB (one batch's E)

  char* ws = (char*)d_ws;
  size_t off = 0;
  unsigned short* query_bf  = (unsigned short*)(ws + off); off += SZ_BF;
  unsigned short* target_bf = (unsigned short*)(ws + off); off += SZ_BF;
  unsigned short* q_bf  = (unsigned short*)(ws + off); off += SZ_BF;
  unsigned short* k_bf  = (unsigned short*)(ws + off); off += SZ_BF;
  unsigned short* v_row = (unsigned short*)(ws + off); off += SZ_BF;  // [16384][512]
  unsigned short* v_t   = (unsigned short*)(ws + off); off += SZ_BF;  // [B][512][4096]
  unsigned short* ctx   = (unsigned short*)(ws + off); off += SZ_BF;
  unsigned short* wq_t  = (unsigned short*)(ws + off); off += 512 * 512 * 2;
  unsigned short* wkv_t = (unsigned short*)(ws + off); off += 2 * 512 * 512 * 2;
  unsigned short* wo_t  = (unsigned short*)(ws + off); off += 512 * 512 * 2;
  float* invl = (float*)(ws + off); off += (size_t)4 * 4096 * sizeof(float);
  off = (off + 255) & ~(size_t)255;
  unsigned short* Sbuf = (unsigned short*)(ws + off);   // NB x 32 MB

  // NB selection identical to R16/R19/R20 (NB=4 engages on this harness).
  const int NB = (ws_size >= off + 4 * SZ_SB) ? 4 : 2;

  // NB=4 aliases (all dead at time of use; rewritten every replay):
  //   partM (8 x 8 MB = 64 MB) over query_bf..k_bf (dead after sexp4)
  //   lsumPart (8 x 16 KB)     over v_row          (dead after vtrans)
  float* partM = (float*)ws;
  float* lsumPart = (float*)(ws + 4 * SZ_BF);
  // NB=2 fallback: 32 MB part over query_bf/target_bf only.
  float* part2 = (float*)ws;

  // 1) inputs -> bf16 (one dispatch); weights -> bf16 transposed ([N][K])
  k_conv2<<<16384, 256, 0, stream>>>(query, target, query_bf, target_bf);
  k_wtrans<<<dim3(1024, 4), 256, 0, stream>>>(wq, wk, wv, wo,
                                              wq_t, wkv_t, wkv_t + 512 * 512, wo_t);

  // 2) merged Q/K/V projection (one dispatch), then V transpose
  k_proj_all<<<dim3(12, 128), 256, 0, stream>>>(query_bf, target_bf, wq_t, wkv_t,
                                                bq, bk, bv, q_bf, k_bf, v_row);
  k_vtrans<<<dim3(8, 256), 256, 0, stream>>>(v_row, v_t);

  if (NB == 4) {
    // 3a) attention tail in 3 launches
    k_sexp4<<<dim3(32, 32, 4), 256, 0, stream>>>(q_bf, k_bf, Sbuf);
    k_pv4<<<dim3(4, 32, 8), 256, 0, stream>>>(Sbuf, v_t, partM, lsumPart);
    k_reduce4<<<8192, 256, 0, stream>>>(partM, lsumPart, ctx);
  } else {
    // 3b) fallback: R16 path
    for (int g = 0; g < 4; g += 2) {
      const unsigned short* qg = q_bf + (size_t)g * 4096 * 512;
      const unsigned short* kg = k_bf + (size_t)g * 4096 * 512;
      k_sexp4<<<dim3(32, 32, 2), 256, 0, stream>>>(qg, kg, Sbuf);
      k_rowsum<<<2 * 4096, 256, 0, stream>>>(Sbuf, invl);
      for (int b2 = 0; b2 < 2; ++b2) {
        const int b = g + b2;
        const unsigned short* Eb  = Sbuf + (size_t)b2 * 4096 * 4096;
        const unsigned short* vtb = v_t + (size_t)b * 512 * 4096;
        unsigned short* ctxb = ctx + (size_t)b * 4096 * 512;
        k_pv<<<dim3(4, 32, 4), 256, 0, stream>>>(Eb, vtb, part2);
        k_reduce_ks<<<2048, 256, 0, stream>>>(part2, invl + (size_t)b2 * 4096, ctxb);
      }
    }
  }

  // 4) output projection (f32 out, bias)
  k_oproj<<<dim3(4, 128), 256, 0, stream>>>(ctx, wo_t, bo, out);
}

// Round 22
// 296.182 us; speedup vs baseline: 1.0114x; 1.0114x over previous
//
#include <hip/hip_runtime.h>
#include <hip/hip_bf16.h>
#include <stdint.h>

#define AS1 __attribute__((address_space(1)))
#define AS3 __attribute__((address_space(3)))

typedef float f32x4 __attribute__((ext_vector_type(4)));
typedef __bf16 bf16x8 __attribute__((ext_vector_type(8)));

static __device__ __forceinline__ unsigned short f2bf(float f) {
  unsigned u = __float_as_uint(f);
  u += 0x7fff + ((u >> 16) & 1);   // RNE
  return (unsigned short)(u >> 16);
}
static __device__ __forceinline__ float bf2f_lo(unsigned u) { return __uint_as_float(u << 16); }
static __device__ __forceinline__ float bf2f_hi(unsigned u) { return __uint_as_float(u & 0xffff0000u); }

// ------------- merged conversion: query and target in one dispatch ----------

__global__ __launch_bounds__(256) void k_conv2(const float* __restrict__ a,
                                               const float* __restrict__ b,
                                               unsigned short* __restrict__ oa,
                                               unsigned short* __restrict__ ob) {
  int i = blockIdx.x * 256 + threadIdx.x;          // 0..4194303 (float4 units)
  const float* in;
  unsigned short* out;
  int idx;
  if (i < 2097152) { in = a; out = oa; idx = i; }
  else             { in = b; out = ob; idx = i - 2097152; }
  float4 v = reinterpret_cast<const float4*>(in)[idx];
  ushort4 o;
  o.x = f2bf(v.x); o.y = f2bf(v.y); o.z = f2bf(v.z); o.w = f2bf(v.w);
  reinterpret_cast<ushort4*>(out)[idx] = o;
}

// transpose + convert the four 512x512 weights: out[n*512+k] = bf16(w[k*512+n])
__global__ __launch_bounds__(256) void k_wtrans(const float* __restrict__ w0, const float* __restrict__ w1,
                                                const float* __restrict__ w2, const float* __restrict__ w3,
                                                unsigned short* __restrict__ o0, unsigned short* __restrict__ o1,
                                                unsigned short* __restrict__ o2, unsigned short* __restrict__ o3) {
  const float* w; unsigned short* o;
  switch (blockIdx.y) {
    case 0: w = w0; o = o0; break;
    case 1: w = w1; o = o1; break;
    case 2: w = w2; o = o2; break;
    default: w = w3; o = o3; break;
  }
  int idx = blockIdx.x * 256 + threadIdx.x;   // 0..262143
  int kk = idx >> 9;
  int n  = idx & 511;
  o[n * 512 + kk] = f2bf(w[idx]);
}

// ---- V transpose: v_row[16384][512] -> v_t[b][512][4096], 64x64 LDS tiles ----

__global__ __launch_bounds__(256) void k_vtrans(const unsigned short* __restrict__ vr,
                                                unsigned short* __restrict__ vt) {
  __shared__ unsigned short lds[64 * 66];    // pad 66: bank-friendly
  const int tid = threadIdx.x;
  const int d0 = blockIdx.x * 64;            // 0..448
  const int s0 = blockIdx.y * 64;            // 0..16320 (tile within one batch)
  const int r = tid >> 4;                    // 0..15
  const int c4 = (tid & 15) * 4;             // 0,4,...,60
#pragma unroll
  for (int i = 0; i < 4; ++i) {
    const int row = i * 16 + r;              // s-offset in tile
    ushort4 v = *reinterpret_cast<const ushort4*>(&vr[(size_t)(s0 + row) * 512 + d0 + c4]);
    lds[row * 66 + c4 + 0] = v.x;
    lds[row * 66 + c4 + 1] = v.y;
    lds[row * 66 + c4 + 2] = v.z;
    lds[row * 66 + c4 + 3] = v.w;
  }
  __syncthreads();
  const int b = s0 >> 12;
  const int sin = s0 & 4095;
#pragma unroll
  for (int i = 0; i < 4; ++i) {
    const int drow = i * 16 + r;             // d-offset in tile
    ushort4 o;
    o.x = lds[(c4 + 0) * 66 + drow];
    o.y = lds[(c4 + 1) * 66 + drow];
    o.z = lds[(c4 + 2) * 66 + drow];
    o.w = lds[(c4 + 3) * 66 + drow];
    *reinterpret_cast<ushort4*>(&vt[(size_t)b * 2097152u + (size_t)(d0 + drow) * 4096u
                                    + sin + c4]) = o;
  }
}

// ---------------- shared GEMM body (EXACT R11 form, unchanged) --------------

template<int EPI, int HAS_BIAS, int SPLITK>
static __device__ __forceinline__ void gemm_body(
    const unsigned short* __restrict__ A, int lda,
    const unsigned short* __restrict__ Bt, int ldb,
    const float* __restrict__ bias,
    void* __restrict__ Cout,
    int ldc, int kLen, int partStride)
{
  __shared__ __align__(16) unsigned short sA[128 * 32];
  __shared__ __align__(16) unsigned short sB[128 * 32];

  const int nx = gridDim.x, ny = gridDim.y;
  const int nwg = nx * ny * gridDim.z;
  const int bid = blockIdx.x + nx * (blockIdx.y + ny * blockIdx.z);
  const int wg = (bid & 7) * (nwg >> 3) + (bid >> 3);
  const int bx = wg % nx;
  const int tmp = wg / nx;
  const int by = tmp % ny;
  const int bz = tmp / ny;

  float* CoutF = (float*)Cout;
  if (SPLITK) {
    A  += (size_t)bz * kLen;
    Bt += (size_t)bz * kLen;
    CoutF += (size_t)bz * partStride;
  }

  const int tid = threadIdx.x;
  const int tileM = by * 128;
  const int tileN = bx * 128;
  const unsigned short* Ab = A + (size_t)tileM * lda;
  const unsigned short* Bb = Bt + (size_t)tileN * ldb;

  f32x4 acc[4][4];
#pragma unroll
  for (int m = 0; m < 4; ++m)
#pragma unroll
    for (int n = 0; n < 4; ++n)
      acc[m][n] = (f32x4){0.f, 0.f, 0.f, 0.f};

  const int lane = tid & 63;
  const int w = tid >> 6;
  const int wr = (w >> 1) * 64;
  const int wc = (w & 1) * 64;
  const int fr = lane & 15;
  const int fk = (lane >> 4) * 8;

  for (int k0 = 0; k0 < kLen; k0 += 32) {
    __syncthreads();
#pragma unroll
    for (int i = 0; i < 2; ++i) {
      int c = tid + i * 256;         // 0..511 (16B chunks)
      int r = c >> 2;
      int cb = (c & 3) * 8;
      __builtin_amdgcn_global_load_lds((const AS1 void*)(Ab + (size_t)r * lda + k0 + cb),
                                       (AS3 void*)(&sA[c * 8]), 16, 0, 0);
      __builtin_amdgcn_global_load_lds((const AS1 void*)(Bb + (size_t)r * ldb + k0 + cb),
                                       (AS3 void*)(&sB[c * 8]), 16, 0, 0);
    }
    __syncthreads();

    bf16x8 af[4], bfr[4];
#pragma unroll
    for (int m = 0; m < 4; ++m)
      af[m] = *reinterpret_cast<const bf16x8*>(&sA[(wr + m * 16 + fr) * 32 + fk]);
#pragma unroll
    for (int n = 0; n < 4; ++n)
      bfr[n] = *reinterpret_cast<const bf16x8*>(&sB[(wc + n * 16 + fr) * 32 + fk]);
#pragma unroll
    for (int m = 0; m < 4; ++m)
#pragma unroll
      for (int n = 0; n < 4; ++n)
        acc[m][n] = __builtin_amdgcn_mfma_f32_16x16x32_bf16(af[m], bfr[n], acc[m][n], 0, 0, 0);
  }

  const int col4 = lane & 15;
  const int rw4 = (lane >> 4) * 4;
#pragma unroll
  for (int n = 0; n < 4; ++n) {
    const int gc = tileN + wc + n * 16 + col4;
    const float bval = HAS_BIAS ? bias[gc] : 0.0f;
#pragma unroll
    for (int m = 0; m < 4; ++m) {
      const int gr0 = tileM + wr + m * 16 + rw4;
#pragma unroll
      for (int j = 0; j < 4; ++j) {
        const int gr = gr0 + j;
        float v = acc[m][n][j] + bval;
        if (EPI == 1) {
          CoutF[(size_t)gr * ldc + gc] = v;
        } else {
          ((unsigned short*)Cout)[(size_t)gr * ldc + gc] = f2bf(v);
        }
      }
    }
  }
}

// ------------- named kernel wrappers (R11 codegen preserved) ----------------

__global__ __launch_bounds__(256) void k_pv(
    const unsigned short* __restrict__ E, const unsigned short* __restrict__ Vt,
    float* __restrict__ part) {
  gemm_body<1, 0, 1>(E, 4096, Vt, 4096, nullptr, part, 512, 1024, 4096 * 512);
}

__global__ __launch_bounds__(256) void k_oproj(
    const unsigned short* __restrict__ A, const unsigned short* __restrict__ Bt,
    const float* __restrict__ bias, float* __restrict__ C) {
  gemm_body<1, 1, 0>(A, 512, Bt, 512, bias, C, 512, 512, 0);
}

// -------- standalone batched S-GEMM: E[bz] = exp(Q[bz] K[bz]^T) -------------
// EXACT R20 form (BK=32, linear LDS, plain scalar-store epilogue). The kernel
// is at its mixed read/write HBM roofline (~293 MB at ~2.5 TB/s ≈ its 120 us):
// R17 (restaged stores), R21 (BK=64 + XOR swizzle, conflicts 8.4M -> 0,
// barriers halved) both left dur unchanged — store pattern, bank conflicts,
// and barrier count are all off the critical path at this occupancy.

__global__ __launch_bounds__(256) void k_sexp4(
    const unsigned short* __restrict__ Q, const unsigned short* __restrict__ K,
    unsigned short* __restrict__ E)
{
  __shared__ __align__(16) unsigned short sA[128 * 32];
  __shared__ __align__(16) unsigned short sB[128 * 32];

  const int nwg = 1024 * gridDim.z;
  const int bid = blockIdx.x + 32 * (blockIdx.y + 32 * blockIdx.z);
  const int wg = (bid & 7) * (nwg >> 3) + (bid >> 3);
  const int bx = wg & 31;
  const int by = (wg >> 5) & 31;
  const int bz = wg >> 10;

  const int tid = threadIdx.x;
  const int tileM = by * 128;
  const int tileN = bx * 128;
  const unsigned short* Ab = Q + (size_t)bz * 2097152u + (size_t)tileM * 512;
  const unsigned short* Bb = K + (size_t)bz * 2097152u + (size_t)tileN * 512;
  unsigned short* Eb = E + (size_t)bz * 16777216u;

  f32x4 acc[4][4];
#pragma unroll
  for (int m = 0; m < 4; ++m)
#pragma unroll
    for (int n = 0; n < 4; ++n)
      acc[m][n] = (f32x4){0.f, 0.f, 0.f, 0.f};

  const int lane = tid & 63;
  const int w = tid >> 6;
  const int wr = (w >> 1) * 64;
  const int wc = (w & 1) * 64;
  const int fr = lane & 15;
  const int fk = (lane >> 4) * 8;

  for (int k0 = 0; k0 < 512; k0 += 32) {
    __syncthreads();
#pragma unroll
    for (int i = 0; i < 2; ++i) {
      int c = tid + i * 256;
      int r = c >> 2;
      int cb = (c & 3) * 8;
      __builtin_amdgcn_global_load_lds((const AS1 void*)(Ab + (size_t)r * 512 + k0 + cb),
                                       (AS3 void*)(&sA[c * 8]), 16, 0, 0);
      __builtin_amdgcn_global_load_lds((const AS1 void*)(Bb + (size_t)r * 512 + k0 + cb),
                                       (AS3 void*)(&sB[c * 8]), 16, 0, 0);
    }
    __syncthreads();

    bf16x8 af[4], bfr[4];
#pragma unroll
    for (int m = 0; m < 4; ++m)
      af[m] = *reinterpret_cast<const bf16x8*>(&sA[(wr + m * 16 + fr) * 32 + fk]);
#pragma unroll
    for (int n = 0; n < 4; ++n)
      bfr[n] = *reinterpret_cast<const bf16x8*>(&sB[(wc + n * 16 + fr) * 32 + fk]);
#pragma unroll
    for (int m = 0; m < 4; ++m)
#pragma unroll
      for (int n = 0; n < 4; ++n)
        acc[m][n] = __builtin_amdgcn_mfma_f32_16x16x32_bf16(af[m], bfr[n], acc[m][n], 0, 0, 0);
  }

  const int col4 = lane & 15;
  const int rw4 = (lane >> 4) * 4;
#pragma unroll
  for (int n = 0; n < 4; ++n) {
    const int gc = tileN + wc + n * 16 + col4;
#pragma unroll
    for (int m = 0; m < 4; ++m) {
      const int gr0 = tileM + wr + m * 16 + rw4;
#pragma unroll
      for (int j = 0; j < 4; ++j)
        Eb[(size_t)(gr0 + j) * 4096 + gc] = f2bf(__expf(acc[m][n][j]));
    }
  }
}

// -------- standalone merged PV (NB=4 path): part[bz] = E-chunk @ V-chunk -----
// R19-validated: one dispatch, 4 batches x 2 K-chunks, fused lsum on bx==0.

__global__ __launch_bounds__(256) void k_pv4(
    const unsigned short* __restrict__ E, const unsigned short* __restrict__ Vt,
    float* __restrict__ part, float* __restrict__ lsumPart)
{
  __shared__ __align__(16) unsigned short sA[128 * 32];
  __shared__ __align__(16) unsigned short sB[128 * 32];

  const int nwg = 1024;
  const int bid = blockIdx.x + 4 * (blockIdx.y + 32 * blockIdx.z);
  const int wg = (bid & 7) * (nwg >> 3) + (bid >> 3);
  const int bx = wg & 3;
  const int tmp = wg >> 2;
  const int by = tmp & 31;
  const int bz = tmp >> 5;          // 0..7
  const int batch = bz >> 1;
  const int kc = bz & 1;

  const int tid = threadIdx.x;
  const int tileM = by * 128;
  const int tileN = bx * 128;
  const unsigned short* Ab = E + (size_t)batch * 16777216u + (size_t)tileM * 4096 + kc * 2048;
  const unsigned short* Bb = Vt + (size_t)batch * 2097152u + (size_t)tileN * 4096 + kc * 2048;
  float* CoutF = part + (size_t)bz * 2097152u;

  f32x4 acc[4][4];
#pragma unroll
  for (int m = 0; m < 4; ++m)
#pragma unroll
    for (int n = 0; n < 4; ++n)
      acc[m][n] = (f32x4){0.f, 0.f, 0.f, 0.f};

  const int lane = tid & 63;
  const int w = tid >> 6;
  const int wr = (w >> 1) * 64;
  const int wc = (w & 1) * 64;
  const int fr = lane & 15;
  const int fk = (lane >> 4) * 8;

  float rs0 = 0.f, rs1 = 0.f;

  for (int k0 = 0; k0 < 2048; k0 += 32) {
    __syncthreads();
#pragma unroll
    for (int i = 0; i < 2; ++i) {
      int c = tid + i * 256;
      int r = c >> 2;
      int cb = (c & 3) * 8;
      __builtin_amdgcn_global_load_lds((const AS1 void*)(Ab + (size_t)r * 4096 + k0 + cb),
                                       (AS3 void*)(&sA[c * 8]), 16, 0, 0);
      __builtin_amdgcn_global_load_lds((const AS1 void*)(Bb + (size_t)r * 4096 + k0 + cb),
                                       (AS3 void*)(&sB[c * 8]), 16, 0, 0);
    }
    __syncthreads();

    if (bx == 0) {
      uint4 u0 = *reinterpret_cast<const uint4*>(&sA[tid * 8]);
      uint4 u1 = *reinterpret_cast<const uint4*>(&sA[(tid + 256) * 8]);
      rs0 += bf2f_lo(u0.x) + bf2f_hi(u0.x) + bf2f_lo(u0.y) + bf2f_hi(u0.y)
           + bf2f_lo(u0.z) + bf2f_hi(u0.z) + bf2f_lo(u0.w) + bf2f_hi(u0.w);
      rs1 += bf2f_lo(u1.x) + bf2f_hi(u1.x) + bf2f_lo(u1.y) + bf2f_hi(u1.y)
           + bf2f_lo(u1.z) + bf2f_hi(u1.z) + bf2f_lo(u1.w) + bf2f_hi(u1.w);
    }

    bf16x8 af[4], bfr[4];
#pragma unroll
    for (int m = 0; m < 4; ++m)
      af[m] = *reinterpret_cast<const bf16x8*>(&sA[(wr + m * 16 + fr) * 32 + fk]);
#pragma unroll
    for (int n = 0; n < 4; ++n)
      bfr[n] = *reinterpret_cast<const bf16x8*>(&sB[(wc + n * 16 + fr) * 32 + fk]);
#pragma unroll
    for (int m = 0; m < 4; ++m)
#pragma unroll
      for (int n = 0; n < 4; ++n)
        acc[m][n] = __builtin_amdgcn_mfma_f32_16x16x32_bf16(af[m], bfr[n], acc[m][n], 0, 0, 0);
  }

  if (bx == 0) {
    rs0 += __shfl_xor(rs0, 1); rs0 += __shfl_xor(rs0, 2);
    rs1 += __shfl_xor(rs1, 1); rs1 += __shfl_xor(rs1, 2);
    if ((tid & 3) == 0) {
      lsumPart[(size_t)bz * 4096 + tileM + (tid >> 2)] = rs0;
      lsumPart[(size_t)bz * 4096 + tileM + (tid >> 2) + 64] = rs1;
    }
  }

  const int col4 = lane & 15;
  const int rw4 = (lane >> 4) * 4;
#pragma unroll
  for (int n = 0; n < 4; ++n) {
    const int gc = tileN + wc + n * 16 + col4;
#pragma unroll
    for (int m = 0; m < 4; ++m) {
      const int gr0 = tileM + wr + m * 16 + rw4;
#pragma unroll
      for (int j = 0; j < 4; ++j)
        CoutF[(size_t)(gr0 + j) * 512 + gc] = acc[m][n][j];
    }
  }
}

// -------- standalone merged Q/K/V projection (R20-validated) ----------------

__global__ __launch_bounds__(256) void k_proj_all(
    const unsigned short* __restrict__ Qin, const unsigned short* __restrict__ Tin,
    const unsigned short* __restrict__ wq_t, const unsigned short* __restrict__ wkv_t,
    const float* __restrict__ bq, const float* __restrict__ bk, const float* __restrict__ bv,
    unsigned short* __restrict__ Qout, unsigned short* __restrict__ Kout,
    unsigned short* __restrict__ Vrow)
{
  __shared__ __align__(16) unsigned short smem[8704];  // sA=[0,4096), sB=[4096,8192); sC reuse

  const int nx = 12, ny = 128;
  const int nwg = nx * ny;                   // 1536, %8==0
  const int bid = blockIdx.x + nx * blockIdx.y;
  const int wg = (bid & 7) * (nwg >> 3) + (bid >> 3);
  const int bx = wg % nx;
  const int by = wg / nx;

  const int tid = threadIdx.x;
  const int tileM = by * 128;
  const unsigned short* A = (bx < 4) ? Qin : Tin;
  const unsigned short* Bt;
  int tileN;
  if (bx < 4) { Bt = wq_t;  tileN = bx * 128; }
  else        { Bt = wkv_t; tileN = (bx - 4) * 128; }
  const unsigned short* Ab = A + (size_t)tileM * 512;
  const unsigned short* Bb = Bt + (size_t)tileN * 512;

  f32x4 acc[4][4];
#pragma unroll
  for (int m = 0; m < 4; ++m)
#pragma unroll
    for (int n = 0; n < 4; ++n)
      acc[m][n] = (f32x4){0.f, 0.f, 0.f, 0.f};

  const int lane = tid & 63;
  const int w = tid >> 6;
  const int wr = (w >> 1) * 64;
  const int wc = (w & 1) * 64;
  const int fr = lane & 15;
  const int fk = (lane >> 4) * 8;

  for (int k0 = 0; k0 < 512; k0 += 32) {
    __syncthreads();
#pragma unroll
    for (int i = 0; i < 2; ++i) {
      int c = tid + i * 256;
      int r = c >> 2;
      int cb = (c & 3) * 8;
      __builtin_amdgcn_global_load_lds((const AS1 void*)(Ab + (size_t)r * 512 + k0 + cb),
                                       (AS3 void*)(&smem[c * 8]), 16, 0, 0);
      __builtin_amdgcn_global_load_lds((const AS1 void*)(Bb + (size_t)r * 512 + k0 + cb),
                                       (AS3 void*)(&smem[4096 + c * 8]), 16, 0, 0);
    }
    __syncthreads();

    bf16x8 af[4], bfr[4];
#pragma unroll
    for (int m = 0; m < 4; ++m)
      af[m] = *reinterpret_cast<const bf16x8*>(&smem[(wr + m * 16 + fr) * 32 + fk]);
#pragma unroll
    for (int n = 0; n < 4; ++n)
      bfr[n] = *reinterpret_cast<const bf16x8*>(&smem[4096 + (wc + n * 16 + fr) * 32 + fk]);
#pragma unroll
    for (int m = 0; m < 4; ++m)
#pragma unroll
      for (int n = 0; n < 4; ++n)
        acc[m][n] = __builtin_amdgcn_mfma_f32_16x16x32_bf16(af[m], bfr[n], acc[m][n], 0, 0, 0);
  }

  const int col4 = lane & 15;
  const int rw4 = (lane >> 4) * 4;
  unsigned short* dst;
  const float* bias;
  int colbase;
  if (bx < 4)      { dst = Qout; bias = bq; colbase = tileN; }
  else if (bx < 8) { dst = Kout; bias = bk; colbase = tileN; }
  else             { dst = Vrow; bias = bv; colbase = tileN - 512; }
  const int lrow = tid >> 2;        // 0..63
  const int chunk = tid & 3;        // 4 x 32 cols
  __syncthreads();                  // MFMA LDS reads retired before sC writes
#pragma unroll
  for (int pass = 0; pass < 2; ++pass) {
    if ((w >> 1) == pass) {
#pragma unroll
      for (int m = 0; m < 4; ++m)
#pragma unroll
        for (int n = 0; n < 4; ++n) {
          const int lc = wc + n * 16 + col4;           // 0..127 within tile
          const float bval = bias[colbase + lc];
#pragma unroll
          for (int j = 0; j < 4; ++j)
            smem[(m * 16 + rw4 + j) * 136 + lc] = f2bf(acc[m][n][j] + bval);
        }
    }
    __syncthreads();
    const int grow = tileM + pass * 64 + lrow;
    unsigned short* drow = dst + (size_t)grow * 512 + colbase + chunk * 32;
#pragma unroll
    for (int i = 0; i < 4; ++i) {
      uint4 u = *reinterpret_cast<const uint4*>(&smem[lrow * 136 + chunk * 32 + i * 8]);
      *reinterpret_cast<uint4*>(drow + i * 8) = u;
    }
    __syncthreads();
  }
}

// ---------------- row sum of E (NB=2 fallback path only) --------------------

__global__ __launch_bounds__(256) void k_rowsum(const unsigned short* __restrict__ E,
                                                float* __restrict__ invl) {
  const int row = blockIdx.x;
  const uint4* p = reinterpret_cast<const uint4*>(E + (size_t)row * 4096);
  const int tid = threadIdx.x;
  float s = 0.f;
#pragma unroll
  for (int i = 0; i < 2; ++i) {
    uint4 u = p[tid + i * 256];
    s += bf2f_lo(u.x) + bf2f_hi(u.x) + bf2f_lo(u.y) + bf2f_hi(u.y)
       + bf2f_lo(u.z) + bf2f_hi(u.z) + bf2f_lo(u.w) + bf2f_hi(u.w);
  }
#pragma unroll
  for (int off = 32; off >= 1; off >>= 1) s += __shfl_xor(s, off);
  __shared__ float reds[4];
  const int wv = tid >> 6, ln = tid & 63;
  if (ln == 0) reds[wv] = s;
  __syncthreads();
  if (tid == 0) {
    float t = reds[0] + reds[1] + reds[2] + reds[3];
    invl[row] = 1.0f / t;
  }
}

// ------- merged split-K reduce + normalization (NB=4 path) ------------------

__global__ __launch_bounds__(256) void k_reduce4(const float* __restrict__ part,
                                                 const float* __restrict__ lsumPart,
                                                 unsigned short* __restrict__ ctx) {
  const int i = blockIdx.x * 256 + threadIdx.x;   // float4 idx, 2097152 total
  const int b = i >> 19;
  const int j = i & 524287;
  const int row = j >> 7;
  const float4* p = reinterpret_cast<const float4*>(part);
  float4 a = p[(size_t)(2 * b) * 524288 + j];
  float4 c = p[(size_t)(2 * b + 1) * 524288 + j];
  const float iv = 1.0f / (lsumPart[(size_t)(2 * b) * 4096 + row]
                         + lsumPart[(size_t)(2 * b + 1) * 4096 + row]);
  ushort4 o;
  o.x = f2bf((a.x + c.x) * iv); o.y = f2bf((a.y + c.y) * iv);
  o.z = f2bf((a.z + c.z) * iv); o.w = f2bf((a.w + c.w) * iv);
  reinterpret_cast<ushort4*>(ctx)[i] = o;
}

// ------- per-batch reduce (NB=2 fallback path only) -------------------------

__global__ __launch_bounds__(256) void k_reduce_ks(const float* __restrict__ part,
                                                   const float* __restrict__ invl,
                                                   unsigned short* __restrict__ out) {
  const int i = blockIdx.x * 256 + threadIdx.x;       // float4 index, 524288 total
  const float4* p = reinterpret_cast<const float4*>(part);
  float4 a = p[i];
  float4 b = p[i + 524288];
  float4 c = p[i + 2 * 524288];
  float4 d = p[i + 3 * 524288];
  const float iv = invl[i >> 7];
  float4 s;
  s.x = ((a.x + b.x) + (c.x + d.x)) * iv;
  s.y = ((a.y + b.y) + (c.y + d.y)) * iv;
  s.z = ((a.z + b.z) + (c.z + d.z)) * iv;
  s.w = ((a.w + b.w) + (c.w + d.w)) * iv;
  ushort4 o;
  o.x = f2bf(s.x); o.y = f2bf(s.y); o.z = f2bf(s.z); o.w = f2bf(s.w);
  reinterpret_cast<ushort4*>(out)[i] = o;
}

// ---------------- launch ----------------

extern "C" void kernel_launch(void* const* d_in, const int* in_sizes, int n_in,
                              void* d_out, int out_size, void* d_ws, size_t ws_size,
                              hipStream_t stream) {
  const float* query  = (const float*)d_in[0];
  const float* target = (const float*)d_in[1];
  const float* wq = (const float*)d_in[2];
  const float* bq = (const float*)d_in[3];
  const float* wk = (const float*)d_in[4];
  const float* bk = (const float*)d_in[5];
  const float* wv = (const float*)d_in[6];
  const float* bv = (const float*)d_in[7];
  const float* wo = (const float*)d_in[8];
  const float* bo = (const float*)d_in[9];
  float* out = (float*)d_out;

  const size_t SZ_BF = (size_t)16384 * 512 * 2;       // 16 MB
  const size_t SZ_SB = (size_t)4096 * 4096 * 2;       // 32 MB (one batch's E)

  char* ws = (char*)d_ws;
  size_t off = 0;
  unsigned short* query_bf  = (unsigned short*)(ws + off); off += SZ_BF;
  unsigned short* target_bf = (unsigned short*)(ws + off); off += SZ_BF;
  unsigned short* q_bf  = (unsigned short*)(ws + off); off += SZ_BF;
  unsigned short* k_bf  = (unsigned short*)(ws + off); off += SZ_BF;
  unsigned short* v_row = (unsigned short*)(ws + off); off += SZ_BF;  // [16384][512]
  unsigned short* v_t   = (unsigned short*)(ws + off); off += SZ_BF;  // [B][512][4096]
  unsigned short* ctx   = (unsigned short*)(ws + off); off += SZ_BF;
  unsigned short* wq_t  = (unsigned short*)(ws + off); off += 512 * 512 * 2;
  unsigned short* wkv_t = (unsigned short*)(ws + off); off += 2 * 512 * 512 * 2;
  unsigned short* wo_t  = (unsigned short*)(ws + off); off += 512 * 512 * 2;
  float* invl = (float*)(ws + off); off += (size_t)4 * 4096 * sizeof(float);
  off = (off + 255) & ~(size_t)255;
  unsigned short* Sbuf = (unsigned short*)(ws + off);   // NB x 32 MB

  // NB selection identical to R16/R19/R20 (NB=4 engages on this harness).
  const int NB = (ws_size >= off + 4 * SZ_SB) ? 4 : 2;

  // NB=4 aliases (all dead at time of use; rewritten every replay):
  //   partM (8 x 8 MB = 64 MB) over query_bf..k_bf (dead after sexp4)
  //   lsumPart (8 x 16 KB)     over v_row          (dead after vtrans)
  float* partM = (float*)ws;
  float* lsumPart = (float*)(ws + 4 * SZ_BF);
  // NB=2 fallback: 32 MB part over query_bf/target_bf only.
  float* part2 = (float*)ws;

  // 1) inputs -> bf16 (one dispatch); weights -> bf16 transposed ([N][K])
  k_conv2<<<16384, 256, 0, stream>>>(query, target, query_bf, target_bf);
  k_wtrans<<<dim3(1024, 4), 256, 0, stream>>>(wq, wk, wv, wo,
                                              wq_t, wkv_t, wkv_t + 512 * 512, wo_t);

  // 2) merged Q/K/V projection (one dispatch), then V transpose
  k_proj_all<<<dim3(12, 128), 256, 0, stream>>>(query_bf, target_bf, wq_t, wkv_t,
                                                bq, bk, bv, q_bf, k_bf, v_row);
  k_vtrans<<<dim3(8, 256), 256, 0, stream>>>(v_row, v_t);

  if (NB == 4) {
    // 3a) attention tail in 3 launches
    k_sexp4<<<dim3(32, 32, 4), 256, 0, stream>>>(q_bf, k_bf, Sbuf);
    k_pv4<<<dim3(4, 32, 8), 256, 0, stream>>>(Sbuf, v_t, partM, lsumPart);
    k_reduce4<<<8192, 256, 0, stream>>>(partM, lsumPart, ctx);
  } else {
    // 3b) fallback: R16 path
    for (int g = 0; g < 4; g += 2) {
      const unsigned short* qg = q_bf + (size_t)g * 4096 * 512;
      const unsigned short* kg = k_bf + (size_t)g * 4096 * 512;
      k_sexp4<<<dim3(32, 32, 2), 256, 0, stream>>>(qg, kg, Sbuf);
      k_rowsum<<<2 * 4096, 256, 0, stream>>>(Sbuf, invl);
      for (int b2 = 0; b2 < 2; ++b2) {
        const int b = g + b2;
        const unsigned short* Eb  = Sbuf + (size_t)b2 * 4096 * 4096;
        const unsigned short* vtb = v_t + (size_t)b * 512 * 4096;
        unsigned short* ctxb = ctx + (size_t)b * 4096 * 512;
        k_pv<<<dim3(4, 32, 4), 256, 0, stream>>>(Eb, vtb, part2);
        k_reduce_ks<<<2048, 256, 0, stream>>>(part2, invl + (size_t)b2 * 4096, ctxb);
      }
    }
  }

  // 4) output projection (f32 out, bias)
  k_oproj<<<dim3(4, 128), 256, 0, stream>>>(ctx, wo_t, bo, out);
}